// Round 4
// 690.667 us; speedup vs baseline: 1.1245x; 1.1245x over previous
//
#include <hip/hip_runtime.h>
#include <cstdint>
#include <cstddef>

typedef unsigned short u16;
typedef __bf16 bf16x8 __attribute__((ext_vector_type(8)));
typedef unsigned int u32;
typedef u32 u32x4 __attribute__((ext_vector_type(4)));
typedef float f32x4v __attribute__((ext_vector_type(4)));

// Problem constants
#define BB 2
#define SS 4096
#define DD 2048
#define HH 16
#define HD 128
#define CC 64
#define NC 64
#define D5 10240
#define RMS_EPS 1.1920928955078125e-07f

__device__ __forceinline__ u16 f2bf(float f) {
  uint32_t x = __float_as_uint(f);
  uint32_t r = (x + 0x7fffu + ((x >> 16) & 1u)) >> 16;
  return (u16)r;
}
__device__ __forceinline__ float bf2f(u16 u) {
  return __uint_as_float(((uint32_t)u) << 16);
}
__device__ __forceinline__ float fast_sigmoid(float x) {
  return 1.0f / (1.0f + __expf(-x));
}
__device__ __forceinline__ float fast_tanh(float x) {
  return 1.0f - 2.0f / (__expf(2.0f * x) + 1.0f);
}

// ---------------------------------------------------------------------------
// fp32 -> bf16 convert, 8 elems/thread (two float4 loads, one uint4 store).
// ---------------------------------------------------------------------------
__global__ void cvt_bf16x8_kernel(const f32x4v* __restrict__ src,
                                  u32x4* __restrict__ dst, int n8) {
  int i = blockIdx.x * blockDim.x + threadIdx.x;
  int stride = gridDim.x * blockDim.x;
  for (; i < n8; i += stride) {
    f32x4v a = src[2 * i];
    f32x4v b = src[2 * i + 1];
    u32x4 o;
    o.x = (u32)f2bf(a.x) | ((u32)f2bf(a.y) << 16);
    o.y = (u32)f2bf(a.z) | ((u32)f2bf(a.w) << 16);
    o.z = (u32)f2bf(b.x) | ((u32)f2bf(b.y) << 16);
    o.w = (u32)f2bf(b.z) | ((u32)f2bf(b.w) << 16);
    dst[i] = o;
  }
}

// ---------------------------------------------------------------------------
// bf16 GEMM, C[M,N] = A[M,K] * B[N,K]^T. 256x256 tile, BK=64, 8 waves (2Mx4N),
// 8-phase schedule, counted vmcnt(8) once per K-tile (never 0 in the loop).
//
// RACE DISCIPLINE (R1/R2 post-mortem — waves' LDS reads interleave across
// the 64-row stage chunks, so no per-region read/stage table is reliable):
//  (1) ALL tile-t+2 stages are issued in q3 only. q3's MFMA runs purely on
//      registers (afr = A-hi from q2, bfr[0] = B-lo from q0). Every LDS read
//      of the current buffer happens in q0-q2; each wave's reads complete
//      (lgkmcnt before its MFMA) before it passes q2's closing barrier; only
//      then can any wave issue the q3 DMA.
//  (2) BARF(): every s_barrier flanked by asm volatile("":::"memory") — no
//      memory op moves across any barrier.
//  (3) sched_barrier(0) after each MFMA cluster — register-only MFMA (and
//      its lgkmcnt wait) cannot sink past the closing barrier (rule #18:
//      "memory" clobbers don't order non-memory ops).
// vmcnt gate: 8 loads issued per iter (q3). At iter t's vmcnt(8):
// outstanding = iter t-1's 8 (tile t+1) + iter t's 8 (tile t+2) -> waits
// until tile t+1 fully landed. Tile t+2 (same parity as t) overwrites
// buffer bo only after all its reads this iter; it is read in iter t+2,
// gated by iter t+1's vmcnt(8).
//
// LDS 128 KiB: 2 bufs x (A[256][64] + B[256][64]) bf16. Swizzle: phys
// 16B-chunk = logical ^ (row&7); global_load_lds writes linear, so the
// swizzle is applied by permuting per-lane global SOURCE chunks; ds_read
// applies the same XOR -> conflict-free b128 reads.
// ---------------------------------------------------------------------------
template <typename OutT>
__global__ __launch_bounds__(512, 2) void gemm_bt(const u16* __restrict__ A,
                                                  const u16* __restrict__ B,
                                                  OutT* __restrict__ C,
                                                  int M, int N, int K) {
  __shared__ u16 lds[65536];  // 128 KiB

  const int tid = threadIdx.x;
  const int wave = tid >> 6;
  const int lane = tid & 63;

  // XCD-aware bijective swizzle (nwg % 8 == 0: 1280 and 256 here)
  const int nwg = (int)gridDim.x;
  const int bid = (int)blockIdx.x;
  const int bswz = (bid & 7) * (nwg >> 3) + (bid >> 3);
  const int Mt = M >> 8;
  const int m0 = (bswz % Mt) << 8;
  const int n0 = (bswz / Mt) << 8;

  // wave output tile: 128 (M) x 64 (N)
  const int wm = (wave >> 2) << 7;
  const int wn = (wave & 3) << 6;

  // ---- staging coords (linear LDS dest; swizzle via global source chunk) ----
  const int s_r = tid >> 3;                // row 0..63 within a 64-row chunk
  const int s_ls = (tid & 7) ^ (s_r & 7);  // logical k-chunk fetched
  const u16* Ast = A + (size_t)(m0 + s_r) * K + s_ls * 8;
  const u16* Bst = B + (size_t)(n0 + s_r) * K + s_ls * 8;
  const int s_lb = wave * 512;             // u16; wave covers 8 rows per inst

  // ---- fragment read coords (16x16x32: row = lane&15, k-grp = lane>>4) ----
  const int fr = lane & 15;
  const int fg = lane >> 4;
  const int fx = lane & 7;
  const int psk0 = ((0 + fg) ^ fx) * 8;    // ks=0 phys chunk, u16 units
  const int psk1 = ((4 + fg) ^ fx) * 8;    // ks=1
  const int aro = (wm + fr) * 64;
  const int bro = 16384 + (wn + fr) * 64;

  f32x4v acc[8][4] = {};
  bf16x8 afr[4][2];        // one A-half at a time
  bf16x8 bfr[2][2][2];     // BOTH B halves resident: [NH][nf][ks]
  const int NT = K >> 6;

// Fenced barrier: no memory op may cross (IR or MIR level).
#define BARF()                              \
  do {                                      \
    asm volatile("" ::: "memory");          \
    __builtin_amdgcn_s_barrier();           \
    asm volatile("" ::: "memory");          \
  } while (0)

#define STAGE(GB, LB, H, KT)                                                    \
  do {                                                                          \
    const u16* g_ = (GB) + (size_t)((H) * 128) * K + (KT) * 64;                 \
    __builtin_amdgcn_global_load_lds(                                           \
        (__attribute__((address_space(1))) void*)(u16*)g_,                      \
        (__attribute__((address_space(3))) void*)&lds[(LB) + (H) * 8192 + s_lb],\
        16, 0, 0);                                                              \
    __builtin_amdgcn_global_load_lds(                                           \
        (__attribute__((address_space(1))) void*)(u16*)(g_ + (size_t)64 * K),   \
        (__attribute__((address_space(3))) void*)&lds[(LB) + (H) * 8192 + 4096 + s_lb], \
        16, 0, 0);                                                              \
  } while (0)

#define LOADA(BO, MH)                                             \
  do {                                                            \
    _Pragma("unroll") for (int mf = 0; mf < 4; ++mf) {            \
      const int ab_ = (BO) + aro + (MH) * 4096 + mf * 1024;       \
      afr[mf][0] = *(const bf16x8*)&lds[ab_ + psk0];              \
      afr[mf][1] = *(const bf16x8*)&lds[ab_ + psk1];              \
    }                                                             \
  } while (0)

#define LOADB(BO, NH)                                             \
  do {                                                            \
    _Pragma("unroll") for (int nf = 0; nf < 2; ++nf) {            \
      const int bb_ = (BO) + bro + (NH) * 2048 + nf * 1024;       \
      bfr[NH][nf][0] = *(const bf16x8*)&lds[bb_ + psk0];          \
      bfr[NH][nf][1] = *(const bf16x8*)&lds[bb_ + psk1];          \
    }                                                             \
  } while (0)

// MFMA cluster; sched_barrier(0) pins it (and its lgkmcnt wait) from sinking
// past the closing s_barrier.
#define MMAQ(MH, NH)                                                          \
  do {                                                                        \
    __builtin_amdgcn_s_setprio(1);                                            \
    _Pragma("unroll") for (int mf = 0; mf < 4; ++mf)                          \
        _Pragma("unroll") for (int nf = 0; nf < 2; ++nf) {                    \
      acc[(MH) * 4 + mf][(NH) * 2 + nf] =                                     \
          __builtin_amdgcn_mfma_f32_16x16x32_bf16(                            \
              afr[mf][0], bfr[NH][nf][0], acc[(MH) * 4 + mf][(NH) * 2 + nf],  \
              0, 0, 0);                                                       \
      acc[(MH) * 4 + mf][(NH) * 2 + nf] =                                     \
          __builtin_amdgcn_mfma_f32_16x16x32_bf16(                            \
              afr[mf][1], bfr[NH][nf][1], acc[(MH) * 4 + mf][(NH) * 2 + nf],  \
              0, 0, 0);                                                       \
    }                                                                         \
    __builtin_amdgcn_s_setprio(0);                                            \
    __builtin_amdgcn_sched_barrier(0);                                        \
  } while (0)

  // Prologue: tiles 0 and 1 fully staged (16 loads/wave); vmcnt(8) -> the 8
  // oldest (= all of K-tile 0) have landed.
  STAGE(Ast, 0, 0, 0);
  STAGE(Ast, 0, 1, 0);
  STAGE(Bst, 16384, 0, 0);
  STAGE(Bst, 16384, 1, 0);
  {
    const int k1 = (NT > 1) ? 1 : 0;
    STAGE(Ast, 32768, 0, k1);
    STAGE(Ast, 32768, 1, k1);
    STAGE(Bst, 49152, 0, k1);
    STAGE(Bst, 49152, 1, k1);
  }
  asm volatile("s_waitcnt vmcnt(8)" ::: "memory");
  BARF();

  for (int t = 0; t < NT; ++t) {
    const int bo = (t & 1) << 15;
    const int t2 = (t + 2 < NT) ? t + 2 : NT - 1;  // tail stages: valid addrs,
                                                   // never consumed

    // q0: (M-lo, N-lo). Reads A-lo + B-lo.
    LOADA(bo, 0);
    LOADB(bo, 0);
    BARF();
    MMAQ(0, 0);
    BARF();

    // q1: (M-lo, N-hi). Reads B-hi.
    LOADB(bo, 1);
    BARF();
    MMAQ(0, 1);
    BARF();

    // q2: (M-hi, N-hi). Reads A-hi.
    LOADA(bo, 1);
    BARF();
    MMAQ(1, 1);
    BARF();

    // q3: (M-hi, N-lo). Pure-register (afr from q2, bfr[0] from q0).
    // Stage ALL of tile t+2 here: every LDS read of this buffer is >= 1
    // fenced barrier in the past. Counted vmcnt once per K-tile: the 8 loads
    // just issued stay in flight; everything older (tile t+1) has landed.
    STAGE(Ast, bo, 0, t2);
    STAGE(Bst, bo + 16384, 0, t2);
    STAGE(Ast, bo, 1, t2);
    STAGE(Bst, bo + 16384, 1, t2);
    BARF();
    MMAQ(1, 0);
    asm volatile("s_waitcnt vmcnt(8)" ::: "memory");
    BARF();
  }

  // Drain outstanding LDS-DMA before kernel exit.
  asm volatile("s_waitcnt vmcnt(0)" ::: "memory");

  // Epilogue: 16x16 C/D layout col=lane&15, row=(lane>>4)*4+reg (m89/m91).
  const int ccol = lane & 15;
  const int crow = (lane >> 4) << 2;
#pragma unroll
  for (int am = 0; am < 8; ++am) {
    const size_t r0 = (size_t)(m0 + wm + ((am >> 2) << 6) + ((am & 3) << 4) + crow);
#pragma unroll
    for (int an = 0; an < 4; ++an) {
      const size_t c0 = (size_t)(n0 + wn + ((an >> 1) << 5) + ((an & 1) << 4) + ccol);
#pragma unroll
      for (int r = 0; r < 4; ++r) {
        OutT* Cp = C + (r0 + r) * (size_t)N + c0;
        if constexpr (sizeof(OutT) == 2)
          *Cp = (OutT)f2bf(acc[am][an][r]);
        else
          *Cp = acc[am][an][r];
      }
    }
  }
#undef BARF
#undef STAGE
#undef LOADA
#undef LOADB
#undef MMAQ
}

// ---------------------------------------------------------------------------
// Scan phase A: per-chunk local pass (state_in = 0):
//   prefix = cumprod(a); acc = cumsum(u / max(prefix,1e-6))
// One wave per (b, chunk, h); lane owns d=lane and d=lane+64.
// ---------------------------------------------------------------------------
__global__ __launch_bounds__(64) void scan_chunk(const u16* __restrict__ proj,
                                                 float* __restrict__ Pc,
                                                 float* __restrict__ Lc) {
  const int idx = blockIdx.x;            // ((b*NC + c)*HH + h)
  const int h = idx & (HH - 1);
  const int c = (idx >> 4) & (NC - 1);
  const int b = idx >> 10;
  const int lane = threadIdx.x;

  const size_t row0 = (size_t)(b * SS + c * CC) * D5 + h * HD;

  float p0 = 1.0f, a0 = 0.0f, p1 = 1.0f, a1 = 0.0f;
  for (int t = 0; t < CC; ++t) {
    const size_t rp = row0 + (size_t)t * D5;
    float k0 = bf2f(proj[rp + DD + lane]);
    float k1 = bf2f(proj[rp + DD + lane + 64]);
    float v0 = bf2f(proj[rp + 2 * DD + lane]);
    float v1 = bf2f(proj[rp + 2 * DD + lane + 64]);
    float ar0 = bf2f(proj[rp + 3 * DD + lane]);
    float ar1 = bf2f(proj[rp + 3 * DD + lane + 64]);
    float aa0 = fminf(fmaxf(fast_sigmoid(ar0 + 2.0f), 0.6f), 0.9995f);
    float aa1 = fminf(fmaxf(fast_sigmoid(ar1 + 2.0f), 0.6f), 0.9995f);
    p0 *= aa0;
    p1 *= aa1;
    a0 += fast_tanh(k0) * v0 / fmaxf(p0, 1e-6f);
    a1 += fast_tanh(k1) * v1 / fmaxf(p1, 1e-6f);
  }
  const size_t ci = ((size_t)(b * NC + c) * HH + h) * HD;  // [b][c][h*hd]
  Pc[ci + lane] = p0;
  Pc[ci + lane + 64] = p1;
  Lc[ci + lane] = p0 * a0;
  Lc[ci + lane + 64] = p1 * a1;
}

// ---------------------------------------------------------------------------
// Scan phase B: inter-chunk carry. One thread per (b, h*hd) channel.
// ---------------------------------------------------------------------------
__global__ void scan_carry(const float* __restrict__ Pc, const float* __restrict__ Lc,
                           float* __restrict__ Sin) {
  const int t = blockIdx.x * blockDim.x + threadIdx.x;  // < BB*DD
  const int b = t >> 11;
  const int hd = t & (DD - 1);
  float state = 0.0f;
  for (int c = 0; c < NC; ++c) {
    const size_t i = (size_t)(b * NC + c) * DD + hd;
    Sin[i] = state;
    state = Pc[i] * state + Lc[i];
  }
}

// ---------------------------------------------------------------------------
// Scan phase C / finalize: recompute chunk-local recurrence, combine with
// carried state: mem_t = prefix_t*(state_in + acc_t); RMS-norm q; gates; y.
// ---------------------------------------------------------------------------
__global__ __launch_bounds__(64) void finalize_y(const u16* __restrict__ proj,
                                                 const float* __restrict__ Sin,
                                                 u16* __restrict__ y) {
  const int idx = blockIdx.x;            // ((b*NC + c)*HH + h)
  const int h = idx & (HH - 1);
  const int c = (idx >> 4) & (NC - 1);
  const int b = idx >> 10;
  const int lane = threadIdx.x;

  const size_t row0 = (size_t)(b * SS + c * CC) * D5 + h * HD;
  const size_t out0 = (size_t)(b * SS + c * CC) * DD + h * HD;
  const size_t sinb = (size_t)(b * NC + c) * DD + h * HD;
  const float sin0 = Sin[sinb + lane];
  const float sin1 = Sin[sinb + lane + 64];

  float p0 = 1.0f, a0 = 0.0f, p1 = 1.0f, a1 = 0.0f;
  for (int t = 0; t < CC; ++t) {
    const size_t rp = row0 + (size_t)t * D5;
    const float q0 = bf2f(proj[rp + lane]);
    const float q1 = bf2f(proj[rp + lane + 64]);
    const float k0 = bf2f(proj[rp + DD + lane]);
    const float k1 = bf2f(proj[rp + DD + lane + 64]);
    const float v0 = bf2f(proj[rp + 2 * DD + lane]);
    const float v1 = bf2f(proj[rp + 2 * DD + lane + 64]);
    const float ar0 = bf2f(proj[rp + 3 * DD + lane]);
    const float ar1 = bf2f(proj[rp + 3 * DD + lane + 64]);
    const float g0 = bf2f(proj[rp + 4 * DD + lane]);
    const float g1 = bf2f(proj[rp + 4 * DD + lane + 64]);

    const float aa0 = fminf(fmaxf(fast_sigmoid(ar0 + 2.0f), 0.6f), 0.9995f);
    const float aa1 = fminf(fmaxf(fast_sigmoid(ar1 + 2.0f), 0.6f), 0.9995f);
    p0 *= aa0;
    p1 *= aa1;
    a0 += fast_tanh(k0) * v0 / fmaxf(p0, 1e-6f);
    a1 += fast_tanh(k1) * v1 / fmaxf(p1, 1e-6f);
    const float mem0 = p0 * (sin0 + a0);
    const float mem1 = p1 * (sin1 + a1);

    float ss = q0 * q0 + q1 * q1;
#pragma unroll
    for (int m = 32; m; m >>= 1) ss += __shfl_xor(ss, m);
    const float rn = rsqrtf(ss * (1.0f / 128.0f) + RMS_EPS);

    const float gt0 = fast_sigmoid(g0);
    const float gt1 = fast_sigmoid(g1);
    y[out0 + (size_t)t * DD + lane] = f2bf(gt0 * (q0 * rn * mem0) + (1.0f - gt0) * v0);
    y[out0 + (size_t)t * DD + lane + 64] = f2bf(gt1 * (q1 * rn * mem1) + (1.0f - gt1) * v1);
  }
}

// ---------------------------------------------------------------------------
extern "C" void kernel_launch(void* const* d_in, const int* in_sizes, int n_in,
                              void* d_out, int out_size, void* d_ws, size_t ws_size,
                              hipStream_t stream) {
  const float* x = (const float*)d_in[0];      // [2,4096,2048]
  const float* w_in = (const float*)d_in[1];   // [10240,2048]
  const float* w_out = (const float*)d_in[2];  // [2048,2048]
  float* out = (float*)d_out;                  // [2,4096,2048] fp32

  char* ws = (char*)d_ws;
  size_t off = 0;
  auto alloc = [&](size_t bytes) -> void* {
    void* p = ws + off;
    off += (bytes + 255) & ~(size_t)255;
    return p;
  };
  const size_t nBS = (size_t)BB * SS;              // 8192
  u16* projb = (u16*)alloc(nBS * D5 * 2);          // 167.8 MB (bf16 proj)
  u16* xb    = (u16*)alloc(nBS * DD * 2);          // 33.6 MB (reused as yb)
  u16* wib   = (u16*)alloc((size_t)D5 * DD * 2);   // 41.9 MB
  u16* wob   = (u16*)alloc((size_t)DD * DD * 2);   // 8.4 MB
  float* Pc  = (float*)alloc((size_t)BB * NC * DD * 4);  // 1 MB
  float* Lc  = (float*)alloc((size_t)BB * NC * DD * 4);  // 1 MB
  float* Sin = (float*)alloc((size_t)BB * NC * DD * 4);  // 1 MB
  u16* yb = xb;  // xb dead after GEMM1; reuse for y
  (void)in_sizes; (void)n_in; (void)out_size;

  // Workspace guard: clean zero-output failure instead of memory fault.
  if (off > ws_size) return;

  // 1) bf16 casts (vectorized: 8 elems/thread)
  cvt_bf16x8_kernel<<<1024, 256, 0, stream>>>((const f32x4v*)x, (u32x4*)xb,
                                              (int)(nBS * DD / 8));
  cvt_bf16x8_kernel<<<1024, 256, 0, stream>>>((const f32x4v*)w_in, (u32x4*)wib,
                                              (int)((size_t)D5 * DD / 8));
  cvt_bf16x8_kernel<<<1024, 256, 0, stream>>>((const f32x4v*)w_out, (u32x4*)wob,
                                              (int)((size_t)DD * DD / 8));

  // 2) proj = x @ w_in^T   [8192 x 10240], K=2048, bf16 out. 256^2 tiles.
  gemm_bt<u16><<<dim3(32 * 40), 512, 0, stream>>>(xb, wib, projb, 8192, 10240, 2048);

  // 3) chunk-local scan -> per-chunk carries only
  scan_chunk<<<BB * NC * HH, 64, 0, stream>>>(projb, Pc, Lc);

  // 4) inter-chunk carry scan
  scan_carry<<<16, 256, 0, stream>>>(Pc, Lc, Sin);

  // 5) finalize y (recompute local scan, rmsnorm q, gates) -> bf16 (into xb)
  finalize_y<<<BB * NC * HH, 64, 0, stream>>>(projb, Sin, yb);

  // 6) out = y @ w_out^T   [8192 x 2048], K=2048, fp32 out. 256^2 tiles.
  gemm_bt<float><<<dim3(32 * 8), 512, 0, stream>>>(yb, wob, out, 8192, 2048, 2048);
}

// Round 5
// 657.472 us; speedup vs baseline: 1.1813x; 1.0505x over previous
//
#include <hip/hip_runtime.h>
#include <cstdint>
#include <cstddef>

typedef unsigned short u16;
typedef __bf16 bf16x8 __attribute__((ext_vector_type(8)));
typedef unsigned int u32;
typedef u32 u32x4 __attribute__((ext_vector_type(4)));
typedef float f32x4v __attribute__((ext_vector_type(4)));

// Problem constants
#define BB 2
#define SS 4096
#define DD 2048
#define HH 16
#define HD 128
#define CC 64
#define NC 64
#define D5 10240
#define RMS_EPS 1.1920928955078125e-07f

__device__ __forceinline__ u16 f2bf(float f) {
  uint32_t x = __float_as_uint(f);
  uint32_t r = (x + 0x7fffu + ((x >> 16) & 1u)) >> 16;
  return (u16)r;
}
__device__ __forceinline__ float bf2f(u16 u) {
  return __uint_as_float(((uint32_t)u) << 16);
}
__device__ __forceinline__ float fast_sigmoid(float x) {
  return 1.0f / (1.0f + __expf(-x));
}
__device__ __forceinline__ float fast_tanh(float x) {
  return 1.0f - 2.0f / (__expf(2.0f * x) + 1.0f);
}

// ---------------------------------------------------------------------------
// fp32 -> bf16 convert, 8 elems/thread (two float4 loads, one uint4 store).
// ---------------------------------------------------------------------------
__global__ void cvt_bf16x8_kernel(const f32x4v* __restrict__ src,
                                  u32x4* __restrict__ dst, int n8) {
  int i = blockIdx.x * blockDim.x + threadIdx.x;
  int stride = gridDim.x * blockDim.x;
  for (; i < n8; i += stride) {
    f32x4v a = src[2 * i];
    f32x4v b = src[2 * i + 1];
    u32x4 o;
    o.x = (u32)f2bf(a.x) | ((u32)f2bf(a.y) << 16);
    o.y = (u32)f2bf(a.z) | ((u32)f2bf(a.w) << 16);
    o.z = (u32)f2bf(b.x) | ((u32)f2bf(b.y) << 16);
    o.w = (u32)f2bf(b.z) | ((u32)f2bf(b.w) << 16);
    dst[i] = o;
  }
}

// ---------------------------------------------------------------------------
// bf16 GEMM, C[M,N] = A[M,K] * B[N,K]^T. 256x256 tile, BK=64, 8 waves (2Mx4N).
// TWO barriers per K-tile (R4 post-mortem: the 8-barrier lockstep left
// MfmaUtil at 43% — barriers between read-quadrants protect nothing, since
// buffer bo is static for the whole iteration; staging happens only after the
// single pre-STAGE barrier).
//
// Iteration structure:
//   open region: all 24 ds_read_b128 of buffer bo + MMAQ(0,0),(0,1),(1,1)
//                — compiler free-schedules (fine-grained lgkmcnt).
//   sched_barrier(0)   — pins MMAQ(1,1)+its lgkm waits above the barrier
//                        (rule #18: "memory" clobbers don't order MFMA).
//   BARF               — all waves' reads of bo complete WG-wide.
//   STAGE x4 (tile t+2 -> bo)  +  MMAQ(1,0) (pure-register quadrant).
//   s_waitcnt vmcnt(8) — 8 loads/iter; oldest 8 outstanding = tile t+1.
//   BARF               — tile t+1 landed WG-wide.
// Race audit: reads only touch bo (content staged iter t-2, landed by iter
// t-1's vmcnt+BARF); BARF (asm memory fences both sides of s_barrier) blocks
// IR/MIR motion of LDS ops across sync points; register anti-deps order
// afr/bfr reuse; q3's MFMA is register-only so the STAGE region contains no
// LDS reads.
//
// LDS 128 KiB: 2 bufs x (A[256][64] + B[256][64]) bf16. Swizzle: phys
// 16B-chunk = logical ^ (row&7); global_load_lds writes linear, so the
// swizzle is applied by permuting per-lane global SOURCE chunks; ds_read
// applies the same XOR -> conflict-free b128 reads (R4: BANK_CONFLICT=0).
//
// Epilogue (bf16 out): per-wave LDS repack (own 16 KB region, chunk-XOR
// swizzled) -> 16x dwordx4 stores per lane, 128B-contiguous — replaces 64
// scalar 2B stores. fp32 out keeps direct scalar stores.
// ---------------------------------------------------------------------------
template <typename OutT>
__global__ __launch_bounds__(512, 2) void gemm_bt(const u16* __restrict__ A,
                                                  const u16* __restrict__ B,
                                                  OutT* __restrict__ C,
                                                  int M, int N, int K) {
  __shared__ u16 lds[65536];  // 128 KiB

  const int tid = threadIdx.x;
  const int wave = tid >> 6;
  const int lane = tid & 63;

  // XCD-aware bijective swizzle (nwg % 8 == 0: 1280 and 256 here)
  const int nwg = (int)gridDim.x;
  const int bid = (int)blockIdx.x;
  const int bswz = (bid & 7) * (nwg >> 3) + (bid >> 3);
  const int Mt = M >> 8;
  const int m0 = (bswz % Mt) << 8;
  const int n0 = (bswz / Mt) << 8;

  // wave output tile: 128 (M) x 64 (N)
  const int wm = (wave >> 2) << 7;
  const int wn = (wave & 3) << 6;

  // ---- staging coords (linear LDS dest; swizzle via global source chunk) ----
  const int s_r = tid >> 3;                // row 0..63 within a 64-row chunk
  const int s_ls = (tid & 7) ^ (s_r & 7);  // logical k-chunk fetched
  const u16* Ast = A + (size_t)(m0 + s_r) * K + s_ls * 8;
  const u16* Bst = B + (size_t)(n0 + s_r) * K + s_ls * 8;
  const int s_lb = wave * 512;             // u16; wave covers 8 rows per inst

  // ---- fragment read coords (16x16x32: row = lane&15, k-grp = lane>>4) ----
  const int fr = lane & 15;
  const int fg = lane >> 4;
  const int fx = lane & 7;
  const int psk0 = ((0 + fg) ^ fx) * 8;    // ks=0 phys chunk, u16 units
  const int psk1 = ((4 + fg) ^ fx) * 8;    // ks=1
  const int aro = (wm + fr) * 64;
  const int bro = 16384 + (wn + fr) * 64;

  f32x4v acc[8][4] = {};
  bf16x8 afr[4][2];        // one A-half at a time
  bf16x8 bfr[2][2][2];     // BOTH B halves resident: [NH][nf][ks]
  const int NT = K >> 6;

// Fenced barrier: no memory op may cross (IR or MIR level).
#define BARF()                              \
  do {                                      \
    asm volatile("" ::: "memory");          \
    __builtin_amdgcn_s_barrier();           \
    asm volatile("" ::: "memory");          \
  } while (0)

#define STAGE(GB, LB, H, KT)                                                    \
  do {                                                                          \
    const u16* g_ = (GB) + (size_t)((H) * 128) * K + (KT) * 64;                 \
    __builtin_amdgcn_global_load_lds(                                           \
        (__attribute__((address_space(1))) void*)(u16*)g_,                      \
        (__attribute__((address_space(3))) void*)&lds[(LB) + (H) * 8192 + s_lb],\
        16, 0, 0);                                                              \
    __builtin_amdgcn_global_load_lds(                                           \
        (__attribute__((address_space(1))) void*)(u16*)(g_ + (size_t)64 * K),   \
        (__attribute__((address_space(3))) void*)&lds[(LB) + (H) * 8192 + 4096 + s_lb], \
        16, 0, 0);                                                              \
  } while (0)

#define LOADA(BO, MH)                                             \
  do {                                                            \
    _Pragma("unroll") for (int mf = 0; mf < 4; ++mf) {            \
      const int ab_ = (BO) + aro + (MH) * 4096 + mf * 1024;       \
      afr[mf][0] = *(const bf16x8*)&lds[ab_ + psk0];              \
      afr[mf][1] = *(const bf16x8*)&lds[ab_ + psk1];              \
    }                                                             \
  } while (0)

#define LOADB(BO, NH)                                             \
  do {                                                            \
    _Pragma("unroll") for (int nf = 0; nf < 2; ++nf) {            \
      const int bb_ = (BO) + bro + (NH) * 2048 + nf * 1024;       \
      bfr[NH][nf][0] = *(const bf16x8*)&lds[bb_ + psk0];          \
      bfr[NH][nf][1] = *(const bf16x8*)&lds[bb_ + psk1];          \
    }                                                             \
  } while (0)

#define MMAQ(MH, NH)                                                          \
  do {                                                                        \
    __builtin_amdgcn_s_setprio(1);                                            \
    _Pragma("unroll") for (int mf = 0; mf < 4; ++mf)                          \
        _Pragma("unroll") for (int nf = 0; nf < 2; ++nf) {                    \
      acc[(MH) * 4 + mf][(NH) * 2 + nf] =                                     \
          __builtin_amdgcn_mfma_f32_16x16x32_bf16(                            \
              afr[mf][0], bfr[NH][nf][0], acc[(MH) * 4 + mf][(NH) * 2 + nf],  \
              0, 0, 0);                                                       \
      acc[(MH) * 4 + mf][(NH) * 2 + nf] =                                     \
          __builtin_amdgcn_mfma_f32_16x16x32_bf16(                            \
              afr[mf][1], bfr[NH][nf][1], acc[(MH) * 4 + mf][(NH) * 2 + nf],  \
              0, 0, 0);                                                       \
    }                                                                         \
    __builtin_amdgcn_s_setprio(0);                                            \
  } while (0)

  // Prologue: tiles 0 and 1 fully staged (16 loads/wave); vmcnt(8) -> the 8
  // oldest (= all of K-tile 0) have landed.
  STAGE(Ast, 0, 0, 0);
  STAGE(Ast, 0, 1, 0);
  STAGE(Bst, 16384, 0, 0);
  STAGE(Bst, 16384, 1, 0);
  {
    const int k1 = (NT > 1) ? 1 : 0;
    STAGE(Ast, 32768, 0, k1);
    STAGE(Ast, 32768, 1, k1);
    STAGE(Bst, 49152, 0, k1);
    STAGE(Bst, 49152, 1, k1);
  }
  asm volatile("s_waitcnt vmcnt(8)" ::: "memory");
  BARF();

  for (int t = 0; t < NT; ++t) {
    const int bo = (t & 1) << 15;
    const int t2 = (t + 2 < NT) ? t + 2 : NT - 1;  // tail stages: valid addrs,
                                                   // never consumed

    // ---- open region: all reads of bo + 3 MFMA quadrants, free-scheduled ----
    LOADA(bo, 0);
    LOADB(bo, 0);
    LOADB(bo, 1);
    MMAQ(0, 0);
    MMAQ(0, 1);
    LOADA(bo, 1);
    MMAQ(1, 1);
    __builtin_amdgcn_sched_barrier(0);  // lgkm waits stay above the barrier
    BARF();  // all waves' reads of bo complete

    // ---- stage tile t+2 into bo; q3 MFMA is pure-register ----
    STAGE(Ast, bo, 0, t2);
    STAGE(Bst, bo + 16384, 0, t2);
    STAGE(Ast, bo, 1, t2);
    STAGE(Bst, bo + 16384, 1, t2);
    MMAQ(1, 0);  // afr from q2's LOADA, bfr[0] from q0's LOADB
    asm volatile("s_waitcnt vmcnt(8)" ::: "memory");
    BARF();  // tile t+1 landed WG-wide
  }

  // Drain outstanding LDS-DMA; after the barrier LDS is reusable.
  asm volatile("s_waitcnt vmcnt(0)" ::: "memory");
  BARF();

  // Epilogue: 16x16 C/D layout col=lane&15, row=(lane>>4)*4+reg (m89/m91).
  const int ccol = lane & 15;
  const int crow = (lane >> 4) << 2;
  if constexpr (sizeof(OutT) == 2) {
    // bf16 out: repack own 128x64 region into own 16 KB LDS slice
    // (chunk-XOR swizzle to spread write banks), then dwordx4 stores.
    u16* wlds = &lds[wave * 8192];
#pragma unroll
    for (int am = 0; am < 8; ++am) {
#pragma unroll
      for (int an = 0; an < 4; ++an) {
        const int col = ((an >> 1) << 5) + ((an & 1) << 4) + ccol;
        const int cch = col >> 3, cre = col & 7;
#pragma unroll
        for (int r = 0; r < 4; ++r) {
          const int row = ((am >> 2) << 6) + ((am & 3) << 4) + crow + r;
          wlds[row * 64 + ((cch ^ (row & 7)) << 3) + cre] =
              f2bf(acc[am][an][r]);
        }
      }
    }
    // Own-region only: no barrier needed; compiler orders ds_write->ds_read.
#pragma unroll
    for (int i = 0; i < 16; ++i) {
      const int row = i * 8 + (lane >> 3);
      const int ch = lane & 7;
      const u32x4 vv = *(const u32x4*)&wlds[row * 64 + (((ch) ^ (row & 7)) << 3)];
      *(u32x4*)(C + (size_t)(m0 + wm + row) * N + (n0 + wn + ch * 8)) = vv;
    }
  } else {
#pragma unroll
    for (int am = 0; am < 8; ++am) {
      const size_t r0 = (size_t)(m0 + wm + ((am >> 2) << 6) + ((am & 3) << 4) + crow);
#pragma unroll
      for (int an = 0; an < 4; ++an) {
        const size_t c0 = (size_t)(n0 + wn + ((an >> 1) << 5) + ((an & 1) << 4) + ccol);
#pragma unroll
        for (int r = 0; r < 4; ++r) {
          OutT* Cp = C + (r0 + r) * (size_t)N + c0;
          *Cp = acc[am][an][r];
        }
      }
    }
  }
#undef BARF
#undef STAGE
#undef LOADA
#undef LOADB
#undef MMAQ
}

// ---------------------------------------------------------------------------
// Scan phase A: per-chunk local pass (state_in = 0):
//   prefix = cumprod(a); acc = cumsum(u / max(prefix,1e-6))
// One wave per (b, chunk, h); lane owns d=lane and d=lane+64.
// ---------------------------------------------------------------------------
__global__ __launch_bounds__(64) void scan_chunk(const u16* __restrict__ proj,
                                                 float* __restrict__ Pc,
                                                 float* __restrict__ Lc) {
  const int idx = blockIdx.x;            // ((b*NC + c)*HH + h)
  const int h = idx & (HH - 1);
  const int c = (idx >> 4) & (NC - 1);
  const int b = idx >> 10;
  const int lane = threadIdx.x;

  const size_t row0 = (size_t)(b * SS + c * CC) * D5 + h * HD;

  float p0 = 1.0f, a0 = 0.0f, p1 = 1.0f, a1 = 0.0f;
  for (int t = 0; t < CC; ++t) {
    const size_t rp = row0 + (size_t)t * D5;
    float k0 = bf2f(proj[rp + DD + lane]);
    float k1 = bf2f(proj[rp + DD + lane + 64]);
    float v0 = bf2f(proj[rp + 2 * DD + lane]);
    float v1 = bf2f(proj[rp + 2 * DD + lane + 64]);
    float ar0 = bf2f(proj[rp + 3 * DD + lane]);
    float ar1 = bf2f(proj[rp + 3 * DD + lane + 64]);
    float aa0 = fminf(fmaxf(fast_sigmoid(ar0 + 2.0f), 0.6f), 0.9995f);
    float aa1 = fminf(fmaxf(fast_sigmoid(ar1 + 2.0f), 0.6f), 0.9995f);
    p0 *= aa0;
    p1 *= aa1;
    a0 += fast_tanh(k0) * v0 / fmaxf(p0, 1e-6f);
    a1 += fast_tanh(k1) * v1 / fmaxf(p1, 1e-6f);
  }
  const size_t ci = ((size_t)(b * NC + c) * HH + h) * HD;  // [b][c][h*hd]
  Pc[ci + lane] = p0;
  Pc[ci + lane + 64] = p1;
  Lc[ci + lane] = p0 * a0;
  Lc[ci + lane + 64] = p1 * a1;
}

// ---------------------------------------------------------------------------
// Scan phase B: inter-chunk carry. One thread per (b, h*hd) channel.
// ---------------------------------------------------------------------------
__global__ void scan_carry(const float* __restrict__ Pc, const float* __restrict__ Lc,
                           float* __restrict__ Sin) {
  const int t = blockIdx.x * blockDim.x + threadIdx.x;  // < BB*DD
  const int b = t >> 11;
  const int hd = t & (DD - 1);
  float state = 0.0f;
  for (int c = 0; c < NC; ++c) {
    const size_t i = (size_t)(b * NC + c) * DD + hd;
    Sin[i] = state;
    state = Pc[i] * state + Lc[i];
  }
}

// ---------------------------------------------------------------------------
// Scan phase C / finalize: recompute chunk-local recurrence, combine with
// carried state: mem_t = prefix_t*(state_in + acc_t); RMS-norm q; gates; y.
// ---------------------------------------------------------------------------
__global__ __launch_bounds__(64) void finalize_y(const u16* __restrict__ proj,
                                                 const float* __restrict__ Sin,
                                                 u16* __restrict__ y) {
  const int idx = blockIdx.x;            // ((b*NC + c)*HH + h)
  const int h = idx & (HH - 1);
  const int c = (idx >> 4) & (NC - 1);
  const int b = idx >> 10;
  const int lane = threadIdx.x;

  const size_t row0 = (size_t)(b * SS + c * CC) * D5 + h * HD;
  const size_t out0 = (size_t)(b * SS + c * CC) * DD + h * HD;
  const size_t sinb = (size_t)(b * NC + c) * DD + h * HD;
  const float sin0 = Sin[sinb + lane];
  const float sin1 = Sin[sinb + lane + 64];

  float p0 = 1.0f, a0 = 0.0f, p1 = 1.0f, a1 = 0.0f;
  for (int t = 0; t < CC; ++t) {
    const size_t rp = row0 + (size_t)t * D5;
    const float q0 = bf2f(proj[rp + lane]);
    const float q1 = bf2f(proj[rp + lane + 64]);
    const float k0 = bf2f(proj[rp + DD + lane]);
    const float k1 = bf2f(proj[rp + DD + lane + 64]);
    const float v0 = bf2f(proj[rp + 2 * DD + lane]);
    const float v1 = bf2f(proj[rp + 2 * DD + lane + 64]);
    const float ar0 = bf2f(proj[rp + 3 * DD + lane]);
    const float ar1 = bf2f(proj[rp + 3 * DD + lane + 64]);
    const float g0 = bf2f(proj[rp + 4 * DD + lane]);
    const float g1 = bf2f(proj[rp + 4 * DD + lane + 64]);

    const float aa0 = fminf(fmaxf(fast_sigmoid(ar0 + 2.0f), 0.6f), 0.9995f);
    const float aa1 = fminf(fmaxf(fast_sigmoid(ar1 + 2.0f), 0.6f), 0.9995f);
    p0 *= aa0;
    p1 *= aa1;
    a0 += fast_tanh(k0) * v0 / fmaxf(p0, 1e-6f);
    a1 += fast_tanh(k1) * v1 / fmaxf(p1, 1e-6f);
    const float mem0 = p0 * (sin0 + a0);
    const float mem1 = p1 * (sin1 + a1);

    float ss = q0 * q0 + q1 * q1;
#pragma unroll
    for (int m = 32; m; m >>= 1) ss += __shfl_xor(ss, m);
    const float rn = rsqrtf(ss * (1.0f / 128.0f) + RMS_EPS);

    const float gt0 = fast_sigmoid(g0);
    const float gt1 = fast_sigmoid(g1);
    y[out0 + (size_t)t * DD + lane] = f2bf(gt0 * (q0 * rn * mem0) + (1.0f - gt0) * v0);
    y[out0 + (size_t)t * DD + lane + 64] = f2bf(gt1 * (q1 * rn * mem1) + (1.0f - gt1) * v1);
  }
}

// ---------------------------------------------------------------------------
extern "C" void kernel_launch(void* const* d_in, const int* in_sizes, int n_in,
                              void* d_out, int out_size, void* d_ws, size_t ws_size,
                              hipStream_t stream) {
  const float* x = (const float*)d_in[0];      // [2,4096,2048]
  const float* w_in = (const float*)d_in[1];   // [10240,2048]
  const float* w_out = (const float*)d_in[2];  // [2048,2048]
  float* out = (float*)d_out;                  // [2,4096,2048] fp32

  char* ws = (char*)d_ws;
  size_t off = 0;
  auto alloc = [&](size_t bytes) -> void* {
    void* p = ws + off;
    off += (bytes + 255) & ~(size_t)255;
    return p;
  };
  const size_t nBS = (size_t)BB * SS;              // 8192
  u16* projb = (u16*)alloc(nBS * D5 * 2);          // 167.8 MB (bf16 proj)
  u16* xb    = (u16*)alloc(nBS * DD * 2);          // 33.6 MB (reused as yb)
  u16* wib   = (u16*)alloc((size_t)D5 * DD * 2);   // 41.9 MB
  u16* wob   = (u16*)alloc((size_t)DD * DD * 2);   // 8.4 MB
  float* Pc  = (float*)alloc((size_t)BB * NC * DD * 4);  // 1 MB
  float* Lc  = (float*)alloc((size_t)BB * NC * DD * 4);  // 1 MB
  float* Sin = (float*)alloc((size_t)BB * NC * DD * 4);  // 1 MB
  u16* yb = xb;  // xb dead after GEMM1; reuse for y
  (void)in_sizes; (void)n_in; (void)out_size;

  // Workspace guard: clean zero-output failure instead of memory fault.
  if (off > ws_size) return;

  // 1) bf16 casts (vectorized: 8 elems/thread)
  cvt_bf16x8_kernel<<<1024, 256, 0, stream>>>((const f32x4v*)x, (u32x4*)xb,
                                              (int)(nBS * DD / 8));
  cvt_bf16x8_kernel<<<1024, 256, 0, stream>>>((const f32x4v*)w_in, (u32x4*)wib,
                                              (int)((size_t)D5 * DD / 8));
  cvt_bf16x8_kernel<<<1024, 256, 0, stream>>>((const f32x4v*)w_out, (u32x4*)wob,
                                              (int)((size_t)DD * DD / 8));

  // 2) proj = x @ w_in^T   [8192 x 10240], K=2048, bf16 out. 256^2 tiles.
  gemm_bt<u16><<<dim3(32 * 40), 512, 0, stream>>>(xb, wib, projb, 8192, 10240, 2048);

  // 3) chunk-local scan -> per-chunk carries only
  scan_chunk<<<BB * NC * HH, 64, 0, stream>>>(projb, Pc, Lc);

  // 4) inter-chunk carry scan
  scan_carry<<<16, 256, 0, stream>>>(Pc, Lc, Sin);

  // 5) finalize y (recompute local scan, rmsnorm q, gates) -> bf16 (into xb)
  finalize_y<<<BB * NC * HH, 64, 0, stream>>>(projb, Sin, yb);

  // 6) out = y @ w_out^T   [8192 x 2048], K=2048, fp32 out. 256^2 tiles.
  gemm_bt<float><<<dim3(32 * 8), 512, 0, stream>>>(yb, wob, out, 8192, 2048, 2048);
}